// Round 1
// baseline (1181.183 us; speedup 1.0000x reference)
//
#include <hip/hip_runtime.h>

// Grouped conv2d: N=16, Cin=256, H=W=128, Cout=512, k=3, groups=16
// Cin/group=16, Cout/group=32, pad=1, stride=1.
// fp32 direct conv, LDS-tiled, register-blocked (2 co x 16 px per lane).

#define CIN_PG 16
#define COUT_PG 32
#define HH 128
#define WW 128
#define TH 8
#define TW 32
#define XTH (TH + 2)   // 10
#define XTW (TW + 2)   // 34
#define XROW 36        // padded row stride (keeps float4 alignment, 2-way banks)
#define WSTR 12        // padded 3x3=9 -> 12 for float4 reads

__global__ __launch_bounds__(256) void grouped_conv_kernel(
    const float* __restrict__ x, const float* __restrict__ wgt,
    const float* __restrict__ bias, float* __restrict__ out)
{
    __shared__ float xs[CIN_PG * XTH * XROW];    // 5760 f = 23 KiB
    __shared__ float ws[CIN_PG * COUT_PG * WSTR]; // 6144 f = 24.5 KiB

    const int bx = blockIdx.x;
    const int wtile = bx & 3;          // 128/32 = 4 w-tiles
    const int htile = (bx >> 2) & 15;  // 128/8  = 16 h-tiles
    const int g = (bx >> 6) & 15;      // 16 groups
    const int n = bx >> 10;            // 16 batch
    const int h0 = htile * TH;
    const int w0 = wtile * TW;
    const int tid = threadIdx.x;

    // ---- stage x tile (halo, zero-padded) ----
    {
        const float* xg = x + (size_t)(n * 256 + g * CIN_PG) * (HH * WW);
        for (int idx = tid; idx < CIN_PG * XTH * XTW; idx += 256) {
            const int ci = idx / (XTH * XTW);
            const int r = idx - ci * (XTH * XTW);
            const int hh = r / XTW;
            const int wwi = r - hh * XTW;
            const int gh = h0 + hh - 1;
            const int gw = w0 + wwi - 1;
            float v = 0.0f;
            if ((unsigned)gh < HH && (unsigned)gw < WW)
                v = xg[(size_t)ci * (HH * WW) + gh * WW + gw];
            xs[(ci * XTH + hh) * XROW + wwi] = v;
        }
    }
    // ---- stage weights: layout ws[ci][co][12] ----
    {
        const float* wg = wgt + (size_t)(g * COUT_PG) * CIN_PG * 9;
        for (int idx = tid; idx < COUT_PG * CIN_PG * 9; idx += 256) {
            const int co = idx / (CIN_PG * 9);
            const int r = idx - co * (CIN_PG * 9);
            const int ci = r / 9;
            const int kk = r - ci * 9;
            ws[(ci * COUT_PG + co) * WSTR + kk] = wg[idx];
        }
    }
    __syncthreads();

    // lane -> (2 co, 16 px) mapping
    const int wave = tid >> 6;
    const int lane = tid & 63;
    const int pg = lane & 15;      // pixel group: oh = pg/2, ow = (pg&1)*16
    const int cp = lane >> 4;      // co-pair within wave
    const int oh = pg >> 1;
    const int ow = (pg & 1) << 4;
    const int co0 = wave * 8 + cp * 2;

    float acc0[16], acc1[16];
#pragma unroll
    for (int j = 0; j < 16; ++j) { acc0[j] = 0.0f; acc1[j] = 0.0f; }

    for (int ci = 0; ci < CIN_PG; ++ci) {
        // weights for this ci, 2 co: 18 registers
        float wr0[9], wr1[9];
        {
            const float4* wp0 = (const float4*)&ws[(ci * COUT_PG + co0) * WSTR];
            float4 a = wp0[0], b = wp0[1], c = wp0[2];
            wr0[0] = a.x; wr0[1] = a.y; wr0[2] = a.z; wr0[3] = a.w;
            wr0[4] = b.x; wr0[5] = b.y; wr0[6] = b.z; wr0[7] = b.w;
            wr0[8] = c.x;
            const float4* wp1 = (const float4*)&ws[(ci * COUT_PG + co0 + 1) * WSTR];
            float4 d = wp1[0], e = wp1[1], f = wp1[2];
            wr1[0] = d.x; wr1[1] = d.y; wr1[2] = d.z; wr1[3] = d.w;
            wr1[4] = e.x; wr1[5] = e.y; wr1[6] = e.z; wr1[7] = e.w;
            wr1[8] = f.x;
        }
#pragma unroll
        for (int kh = 0; kh < 3; ++kh) {
            const int rb = (ci * XTH + oh + kh) * XROW + ow;
            const float4* xp = (const float4*)&xs[rb];
            float4 x0 = xp[0], x1 = xp[1], x2 = xp[2], x3 = xp[3];
            float xv[18] = {x0.x, x0.y, x0.z, x0.w, x1.x, x1.y, x1.z, x1.w,
                            x2.x, x2.y, x2.z, x2.w, x3.x, x3.y, x3.z, x3.w,
                            xs[rb + 16], xs[rb + 17]};
#pragma unroll
            for (int kw = 0; kw < 3; ++kw) {
                const float w0v = wr0[kh * 3 + kw];
                const float w1v = wr1[kh * 3 + kw];
#pragma unroll
                for (int j = 0; j < 16; ++j) {
                    acc0[j] = fmaf(xv[j + kw], w0v, acc0[j]);
                    acc1[j] = fmaf(xv[j + kw], w1v, acc1[j]);
                }
            }
        }
    }

    // ---- epilogue: bias + store ----
    const float b0 = bias[g * COUT_PG + co0];
    const float b1 = bias[g * COUT_PG + co0 + 1];
    const size_t plane = (size_t)(HH * WW);
    float* o0 = out + ((size_t)n * 512 + g * COUT_PG + co0) * plane
              + (size_t)(h0 + oh) * WW + (w0 + ow);
    float* o1 = o0 + plane;
#pragma unroll
    for (int v = 0; v < 4; ++v) {
        float4 t0 = {acc0[4 * v + 0] + b0, acc0[4 * v + 1] + b0,
                     acc0[4 * v + 2] + b0, acc0[4 * v + 3] + b0};
        float4 t1 = {acc1[4 * v + 0] + b1, acc1[4 * v + 1] + b1,
                     acc1[4 * v + 2] + b1, acc1[4 * v + 3] + b1};
        *(float4*)&o0[4 * v] = t0;
        *(float4*)&o1[4 * v] = t1;
    }
}

extern "C" void kernel_launch(void* const* d_in, const int* in_sizes, int n_in,
                              void* d_out, int out_size, void* d_ws, size_t ws_size,
                              hipStream_t stream) {
    const float* x = (const float*)d_in[0];
    const float* w = (const float*)d_in[1];
    const float* b = (const float*)d_in[2];
    float* out = (float*)d_out;
    // blocks: 16 n * 16 g * 16 h-tiles * 4 w-tiles = 16384
    hipLaunchKernelGGL(grouped_conv_kernel, dim3(16384), dim3(256), 0, stream,
                       x, w, b, out);
}